// Round 6
// baseline (2170.425 us; speedup 1.0000x reference)
//
#include <hip/hip_runtime.h>
#include <hip/hip_bf16.h>
#include <hip/hip_fp16.h>
#include <math.h>

#define V_SIZE 50257
#define V_PAD  50304   // 393*128
#define E_DIM  256
#define H_DIM  512
#define G_DIM  1536
#define B_SZ   4
#define S_LEN  512

typedef __attribute__((ext_vector_type(8))) short bf16x8;
typedef __attribute__((ext_vector_type(4))) float f32x4;
typedef __attribute__((ext_vector_type(2))) _Float16 h16x2;

__device__ __forceinline__ float bf2f(unsigned short u) {
  union { unsigned int i; float f; } x; x.i = ((unsigned int)u) << 16; return x.f;
}
__device__ __forceinline__ unsigned short f2bf(float f) {
  __hip_bfloat16 h = __float2bfloat16(f);   // RNE
  return reinterpret_cast<unsigned short&>(h);
}
__device__ __forceinline__ float sigmoidf_(float x) { return 1.0f / (1.0f + expf(-x)); }
// fast variants for the scan's epilogue (err ~1e-7 rel, threshold is 2e-2)
__device__ __forceinline__ float fsig(float x) { return 1.0f / (1.0f + __expf(-x)); }
__device__ __forceinline__ float ftanh(float x) { return 1.0f - 2.0f / (__expf(2.0f * x) + 1.0f); }

__device__ __forceinline__ h16x2 as_h2(unsigned int u) {
  union { unsigned int u; h16x2 h; } x; x.u = u; return x.h;
}

#if defined(__has_builtin)
#if __has_builtin(__builtin_amdgcn_fdot2)
#define HAVE_FDOT2 1
#endif
#endif
__device__ __forceinline__ float fdot2_(unsigned int a, unsigned int b, float c) {
#ifdef HAVE_FDOT2
  return __builtin_amdgcn_fdot2(as_h2(a), as_h2(b), c, false);
#else
  h16x2 ha = as_h2(a), hb = as_h2(b);
  return c + (float)ha[0] * (float)hb[0] + (float)ha[1] * (float)hb[1];
#endif
}

__device__ __forceinline__ void gload_lds16(const void* g, void* l) {
  __builtin_amdgcn_global_load_lds((const __attribute__((address_space(1))) unsigned int*)g,
                                   (__attribute__((address_space(3))) unsigned int*)l, 16, 0, 0);
}

// ---------------- embedding fp32 -> bf16 (padded to V_PAD rows) ----------------
__global__ __launch_bounds__(256) void k_emb2bf(const float* __restrict__ emb,
                                                __hip_bfloat16* __restrict__ out) {
  const long total = (long)V_PAD * E_DIM;
  for (long i = (long)blockIdx.x * 256 + threadIdx.x; i < total; i += (long)gridDim.x * 256) {
    int row = (int)(i >> 8);
    float v = (row < V_SIZE) ? emb[i] : 0.0f;
    out[i] = __float2bfloat16(v);
  }
}

// ---------------- xg = emb[ids] @ W_ih^T + b_ih  (fp32) ----------------
// grid (12, 128), block 256. tile: 128 g x 16 n, K=256
__global__ __launch_bounds__(256) void k_xg(const int* __restrict__ ids, const float* __restrict__ emb,
                                            const float* __restrict__ W_ih, const float* __restrict__ b_ih,
                                            float* __restrict__ xg) {
  __shared__ float embs[16][260];
  __shared__ float wl[64][133];
  const int g0 = blockIdx.x * 128, n0 = blockIdx.y * 16, tid = threadIdx.x;
  for (int idx = tid; idx < 16 * 256; idx += 256) {
    int n = idx >> 8, e = idx & 255;
    embs[n][e] = emb[(long)ids[n0 + n] * E_DIM + e];
  }
  const int g = tid & 127, ng = tid >> 7;
  float acc[8] = {0.f,0.f,0.f,0.f,0.f,0.f,0.f,0.f};
  for (int e0 = 0; e0 < 256; e0 += 64) {
    __syncthreads();
    for (int idx = tid; idx < 128 * 64; idx += 256) {
      int r = idx >> 6, c = idx & 63;
      wl[c][r] = W_ih[(long)(g0 + r) * E_DIM + e0 + c];
    }
    __syncthreads();
    for (int c = 0; c < 64; ++c) {
      float w = wl[c][g];
      #pragma unroll
      for (int j = 0; j < 8; ++j) acc[j] += w * embs[ng * 8 + j][e0 + c];
    }
  }
  const float bias = b_ih[g0 + g];
  #pragma unroll
  for (int j = 0; j < 8; ++j) {
    int n = n0 + ng * 8 + j;
    xg[(long)n * G_DIM + g0 + g] = acc[j] + bias;
  }
}

// ---------------- persistent GRU scan: 32 wgs x 512 thr ----------------
// u64-packed data-is-the-flag protocol (R5) + R6 distributed tail:
// after the single per-step barrier, wave w finalizes rows {2w, 2w+1}
// itself (3 LDS partial reads + 3-round kt-butterfly + parallel epilogue
// + its own 2-row publish) instead of funneling everything through wave 0.
#define NWG 32
#define WROWU 261                 // W row stride in u32 pairs (bank-spread)
#define WPLU  (16 * WROWU)
#define HROWU 260                 // hp row stride in u32 pairs
__global__ __launch_bounds__(512, 1) void k_scan(const float* __restrict__ xg,
                                                 const float* __restrict__ W_hh,
                                                 const float* __restrict__ b_hh,
                                                 float* __restrict__ states,
                                                 unsigned long long* __restrict__ h_hist) {
  __shared__ unsigned int Wp[3 * WPLU];         // 50,112 B (f16 pairs)
  __shared__ unsigned int hp[4 * HROWU];        //  4,160 B (f16 pairs, per-wave-private slices)
  __shared__ float red[2][16][8][13];           // 13,312 B partials: [buf][row][srcwave][q*4+b]
  const int wg = blockIdx.x, tid = threadIdx.x;
  const int i0 = wg * 16;
  // stage W slice as f16 pairs
  for (int e = tid; e < 3 * 16 * 256; e += 512) {
    int q = e >> 12, i = (e >> 8) & 15, p = e & 255;
    float2 w2 = reinterpret_cast<const float2*>(W_hh + (long)((q << 9) + i0 + i) * H_DIM)[p];
    unsigned int pk = (unsigned int)__half_as_ushort(__float2half(w2.x)) |
                      ((unsigned int)__half_as_ushort(__float2half(w2.y)) << 16);
    Wp[q * WPLU + i * WROWU + p] = pk;
  }
  const int wave = tid >> 6, l = tid & 63, il = l >> 2, part = l & 3;
  const int pidx = tid >> 1;                    // pair index this thread fills
  // distributed-tail lane mapping: wave w owns rows {2w, 2w+1}
  const int rl  = l >> 5;                       // row within wave's pair
  const int bbt = (l >> 3) & 3;                 // batch
  const int kt  = l & 7;                        // source-wave reduce lane
  const int rowg = 2 * wave + rl;               // row-local in wg [0,16)
  float h_prev = 0.0f;                          // redundant across the 8 kt lanes
  const float bhr = b_hh[i0 + rowg];
  const float bhz = b_hh[512 + i0 + rowg];
  const float bhn = b_hh[1024 + i0 + rowg];
  __syncthreads();

  for (int t = 0; t < S_LEN; ++t) {
    // xg prefetch for this lane's (row,batch) — in flight during poll+MAC
    const float* xgrow = xg + (long)(bbt * S_LEN + t) * G_DIM + i0 + rowg;
    const float xr_v = xgrow[0], xz_v = xgrow[512], xn_v = xgrow[1024];
    float acc[3][4] = {{0.f,0.f,0.f,0.f},{0.f,0.f,0.f,0.f},{0.f,0.f,0.f,0.f}};
    if (t > 0) {
      // one u64 poll per thread: h[0..3][hidx=tid] for step t-1
      const unsigned long long* hb = h_hist + (long)(t - 1) * 512;
      unsigned long long v;
      do {
        v = __hip_atomic_load(hb + tid, __ATOMIC_RELAXED, __HIP_MEMORY_SCOPE_AGENT);
      } while (v == 0xFFFFFFFFFFFFFFFFull);
      const unsigned int lo = (unsigned int)v, hi = (unsigned int)(v >> 32);
      const unsigned int plo = __shfl_xor(lo, 1), phi = __shfl_xor(hi, 1);
      if ((tid & 1) == 0) {       // even: build batch 0,1 pairs for (c, c+1)
        hp[pidx]         = (lo & 0xffffu) | (plo << 16);
        hp[HROWU + pidx] = (lo >> 16) | (plo & 0xffff0000u);
      } else {                    // odd: build batch 2,3 pairs
        hp[2 * HROWU + pidx] = (phi & 0xffffu) | (hi << 16);
        hp[3 * HROWU + pidx] = (phi >> 16) | (hi & 0xffff0000u);
      }
      // per-wave-private LDS region: wave-synchronous RAW, no barrier
      const int pbase = (wave << 5) + (part << 3);
      #pragma unroll
      for (int j = 0; j < 8; ++j) {
        const int p = pbase + j;
        const unsigned int w_r = Wp[il * WROWU + p];
        const unsigned int w_z = Wp[WPLU + il * WROWU + p];
        const unsigned int w_n = Wp[2 * WPLU + il * WROWU + p];
        const unsigned int h0 = hp[p];
        const unsigned int h1 = hp[HROWU + p];
        const unsigned int h2 = hp[2 * HROWU + p];
        const unsigned int h3 = hp[3 * HROWU + p];
        acc[0][0] = fdot2_(w_r, h0, acc[0][0]); acc[0][1] = fdot2_(w_r, h1, acc[0][1]);
        acc[0][2] = fdot2_(w_r, h2, acc[0][2]); acc[0][3] = fdot2_(w_r, h3, acc[0][3]);
        acc[1][0] = fdot2_(w_z, h0, acc[1][0]); acc[1][1] = fdot2_(w_z, h1, acc[1][1]);
        acc[1][2] = fdot2_(w_z, h2, acc[1][2]); acc[1][3] = fdot2_(w_z, h3, acc[1][3]);
        acc[2][0] = fdot2_(w_n, h0, acc[2][0]); acc[2][1] = fdot2_(w_n, h1, acc[2][1]);
        acc[2][2] = fdot2_(w_n, h2, acc[2][2]); acc[2][3] = fdot2_(w_n, h3, acc[2][3]);
      }
    }
    // reduce over 'part' (4 lanes), stash per-wave partials
    #pragma unroll
    for (int q = 0; q < 3; ++q)
      #pragma unroll
      for (int b = 0; b < 4; ++b) {
        float v = acc[q][b];
        v += __shfl_xor(v, 1);
        v += __shfl_xor(v, 2);
        if (part == 0) red[t & 1][il][wave][q * 4 + b] = v;
      }
    __syncthreads();                             // the ONE barrier per step
    // ---- distributed tail: wave w finalizes rows {2w, 2w+1} ----
    float hr = red[t & 1][rowg][kt][0 + bbt];
    float hz = red[t & 1][rowg][kt][4 + bbt];
    float hn = red[t & 1][rowg][kt][8 + bbt];
    hr += __shfl_xor(hr, 1); hr += __shfl_xor(hr, 2); hr += __shfl_xor(hr, 4);
    hz += __shfl_xor(hz, 1); hz += __shfl_xor(hz, 2); hz += __shfl_xor(hz, 4);
    hn += __shfl_xor(hn, 1); hn += __shfl_xor(hn, 2); hn += __shfl_xor(hn, 4);
    const float r  = fsig(xr_v + bhr + hr);
    const float z  = fsig(xz_v + bhz + hz);
    const float nn = ftanh(xn_v + bhn + hn);
    const float h_new = (1.0f - z) * nn + z * h_prev;
    h_prev = h_new;
    // publish FIRST (critical path): gather 4 batches into one u64 per row
    const unsigned int hu = (unsigned int)__half_as_ushort(__float2half(h_new));
    const unsigned int p01 = hu | (__shfl_xor(hu, 8) << 16);   // at bbt=0: (b0,b1); bbt=2: (b2,b3)
    const unsigned int p23 = __shfl_xor(p01, 16);              // at bbt=0: (b2,b3)
    if (bbt == 0 && kt == 0) {
      unsigned long long pk = (unsigned long long)p01 | ((unsigned long long)p23 << 32);
      __hip_atomic_store(h_hist + (long)t * 512 + i0 + rowg, pk,
                         __ATOMIC_RELAXED, __HIP_MEMORY_SCOPE_AGENT);
    }
    if (kt == 0) states[(long)(bbt * S_LEN + t) * H_DIM + i0 + rowg] = h_new;
    // no trailing barrier: hp per-wave-private, red double-buffered (barrier-chain safe)
  }
}

// ---------------- read/decay/write gates (wave-per-row, coalesced) ----------------
__global__ __launch_bounds__(256) void k_gates(const float* __restrict__ states,
     const float* __restrict__ W_read, const float* __restrict__ b_read,
     const float* __restrict__ W_write, const float* __restrict__ b_write,
     const float* __restrict__ W_decay, const float* __restrict__ b_decay,
     const float* __restrict__ mscale,
     float* __restrict__ read_s, float* __restrict__ decay_s, float* __restrict__ write_s) {
  __shared__ float wr[512], ww[512], wd[512];
  const int tid = threadIdx.x;
  for (int i = tid; i < 512; i += 256) { wr[i] = W_read[i]; ww[i] = W_write[i]; wd[i] = W_decay[i]; }
  __syncthreads();
  const int wave = tid >> 6, l = tid & 63;
  const float br = b_read[0], bw = b_write[0], bd = b_decay[0], ms = mscale[0];
  for (int r = 0; r < 16; ++r) {
    const int n = blockIdx.x * 64 + wave * 16 + r;
    const float* st = states + (long)n * H_DIM;
    float ar = 0.f, aw = 0.f, ad = 0.f;
    #pragma unroll
    for (int h0 = 0; h0 < 512; h0 += 64) {
      float s = st[h0 + l];
      ar += s * wr[h0 + l]; aw += s * ww[h0 + l]; ad += s * wd[h0 + l];
    }
    #pragma unroll
    for (int k = 1; k < 64; k <<= 1) {
      ar += __shfl_xor(ar, k); aw += __shfl_xor(aw, k); ad += __shfl_xor(ad, k);
    }
    if (l == 0) {
      read_s[n]  = sigmoidf_(ar + br) * ms;
      write_s[n] = sigmoidf_(aw + bw);
      decay_s[n] = sigmoidf_(ad + bd);
    }
  }
}

// ---------------- proj = states @ W_he^T + b_he -> bf16 ----------------
__global__ __launch_bounds__(256) void k_proj(const float* __restrict__ states,
                                              const float* __restrict__ W_he,
                                              const float* __restrict__ b_he,
                                              __hip_bfloat16* __restrict__ proj) {
  __shared__ float sts[32][64];
  __shared__ float wle[64][69];
  const int n0 = blockIdx.x * 32, e0 = blockIdx.y * 64, tid = threadIdx.x;
  const int e = tid & 63, ng = tid >> 6;
  float acc[8] = {0.f,0.f,0.f,0.f,0.f,0.f,0.f,0.f};
  for (int h0 = 0; h0 < 512; h0 += 64) {
    __syncthreads();
    for (int idx = tid; idx < 32 * 64; idx += 256) {
      int n = idx >> 6, c = idx & 63;
      sts[n][c] = states[(long)(n0 + n) * H_DIM + h0 + c];
    }
    for (int idx = tid; idx < 64 * 64; idx += 256) {
      int r = idx >> 6, c = idx & 63;
      wle[c][r] = W_he[(long)(e0 + r) * H_DIM + h0 + c];
    }
    __syncthreads();
    for (int c = 0; c < 64; ++c) {
      float w = wle[c][e];
      #pragma unroll
      for (int j = 0; j < 8; ++j) acc[j] += w * sts[ng * 8 + j][c];
    }
  }
  const float bias = b_he[e0 + e];
  #pragma unroll
  for (int j = 0; j < 8; ++j) {
    int n = n0 + ng * 8 + j;
    proj[(long)n * E_DIM + e0 + e] = __float2bfloat16(acc[j] + bias);
  }
}

// ---------------- base = proj @ emb^T + output_bias (bf16 MFMA) ----------------
// grid (393, 16), block 256 (4 waves 2x2), tile 128x128, BK=32, K=256
__global__ __launch_bounds__(256) void k_base(const __hip_bfloat16* __restrict__ A,
                                              const __hip_bfloat16* __restrict__ Bm,
                                              const float* __restrict__ obias,
                                              float* __restrict__ C) {
  __shared__ unsigned short As[128 * 32], Bs[128 * 32];
  const int n0 = blockIdx.x * 128, m0 = blockIdx.y * 128, tid = threadIdx.x;
  const int wid = tid >> 6, l = tid & 63;
  const int wm = wid >> 1, wn = wid & 1;
  f32x4 acc[4][4];
  #pragma unroll
  for (int mi = 0; mi < 4; ++mi)
    #pragma unroll
    for (int ni = 0; ni < 4; ++ni) acc[mi][ni] = (f32x4){0.f, 0.f, 0.f, 0.f};

  for (int kk = 0; kk < 256; kk += 32) {
    __syncthreads();
    #pragma unroll
    for (int s = 0; s < 2; ++s) {
      const int cibase = wid * 128 + s * 64;
      const int ci = cibase + l;
      const int row = ci >> 2, cq = ci & 3;
      gload_lds16(A + (long)(m0 + row) * E_DIM + kk + cq * 8, As + cibase * 8);
      gload_lds16(Bm + (long)(n0 + row) * E_DIM + kk + cq * 8, Bs + cibase * 8);
    }
    __syncthreads();
    bf16x8 af[4], bfr[4];
    const int krow = (l >> 4) * 8;
    #pragma unroll
    for (int mi = 0; mi < 4; ++mi) {
      int row = wm * 64 + mi * 16 + (l & 15);
      af[mi] = *reinterpret_cast<const bf16x8*>(&As[row * 32 + krow]);
    }
    #pragma unroll
    for (int ni = 0; ni < 4; ++ni) {
      int row = wn * 64 + ni * 16 + (l & 15);
      bfr[ni] = *reinterpret_cast<const bf16x8*>(&Bs[row * 32 + krow]);
    }
    #pragma unroll
    for (int mi = 0; mi < 4; ++mi)
      #pragma unroll
      for (int ni = 0; ni < 4; ++ni)
        acc[mi][ni] = __builtin_amdgcn_mfma_f32_16x16x32_bf16(af[mi], bfr[ni], acc[mi][ni], 0, 0, 0);
  }
  #pragma unroll
  for (int mi = 0; mi < 4; ++mi) {
    const int rowb = m0 + wm * 64 + mi * 16 + (l >> 4) * 4;
    #pragma unroll
    for (int ni = 0; ni < 4; ++ni) {
      const int col = n0 + wn * 64 + ni * 16 + (l & 15);
      if (col < V_SIZE) {
        const float ob = obias[col];
        #pragma unroll
        for (int r = 0; r < 4; ++r)
          C[(long)(rowb + r) * V_SIZE + col] = acc[mi][ni][r] + ob;
      }
    }
  }
}

// ---------------- sparse memory correction: out[b,t,v] += read*m ----------------
// grid (4 batches, 8 owner-chunks) x 64 threads: owner-per-lane
__global__ __launch_bounds__(64) void k_corr(const int* __restrict__ ids,
                                             const float* __restrict__ read_s,
                                             const float* __restrict__ decay_s,
                                             const float* __restrict__ write_s,
                                             float* __restrict__ out) {
  __shared__ int ids_s[512];
  __shared__ float rd[512], dc[512], wrs[512];
  const int b = blockIdx.x, c = blockIdx.y, l = threadIdx.x;
  for (int t = l; t < 512; t += 64) {
    int n = b * 512 + t;
    ids_s[t] = ids[n]; rd[t] = read_s[n]; dc[t] = decay_s[n]; wrs[t] = write_s[n];
  }
  __syncthreads();
  const int j = c * 64 + l;
  const int v = ids_s[j];
  for (int jj = 0; jj < j; ++jj) if (ids_s[jj] == v) return;  // not the owner
  float m = wrs[j];
  float* outb = out + (long)b * S_LEN * V_SIZE + v;
  for (int t = j + 1; t < 512; ++t) {
    outb[(long)t * V_SIZE] += rd[t] * m;
    m *= dc[t];
    if (ids_s[t] == v) m += wrs[t];
  }
}

extern "C" void kernel_launch(void* const* d_in, const int* in_sizes, int n_in,
                              void* d_out, int out_size, void* d_ws, size_t ws_size,
                              hipStream_t stream) {
  const int*   ids     = (const int*)d_in[0];
  const float* emb     = (const float*)d_in[1];
  const float* W_ih    = (const float*)d_in[2];
  const float* W_hh    = (const float*)d_in[3];
  const float* b_ih    = (const float*)d_in[4];
  const float* b_hh    = (const float*)d_in[5];
  const float* W_he    = (const float*)d_in[6];
  const float* b_he    = (const float*)d_in[7];
  const float* obias   = (const float*)d_in[8];
  const float* W_read  = (const float*)d_in[9];
  const float* b_read  = (const float*)d_in[10];
  const float* W_write = (const float*)d_in[11];
  const float* b_write = (const float*)d_in[12];
  const float* W_decay = (const float*)d_in[13];
  const float* b_decay = (const float*)d_in[14];
  const float* mscale  = (const float*)d_in[15];

  // ws: emb_bf16 (25.7MB) + proj_bf16 (1MB) + gate scalars (24KB)
  char* ws = (char*)d_ws;
  __hip_bfloat16* emb_bf  = (__hip_bfloat16*)ws;                    // V_PAD*E*2 = 25,755,648
  __hip_bfloat16* proj_bf = (__hip_bfloat16*)(ws + 25755648);       // 1,048,576
  float* read_s  = (float*)(ws + 26804224);
  float* decay_s = (float*)(ws + 26812416);
  float* write_s = (float*)(ws + 26820608);

  // scratch that dies before k_base lives inside d_out (412MB):
  char* ob = (char*)d_out;
  float* xg  = (float*)ob;                                   // 12,582,912 B
  float* states = (float*)(ob + 12582912);                   //  4,194,304 B
  unsigned long long* h_hist = (unsigned long long*)(ob + 16777216); // 512*512*8 = 2,097,152 B
  float* out = (float*)d_out;

  hipMemsetAsync(h_hist, 0xFF, (size_t)S_LEN * 512 * sizeof(unsigned long long), stream);
  k_emb2bf<<<2048, 256, 0, stream>>>(emb, emb_bf);
  dim3 gxg(12, 128);
  k_xg<<<gxg, 256, 0, stream>>>(ids, emb, W_ih, b_ih, xg);
  k_scan<<<NWG, 512, 0, stream>>>(xg, W_hh, b_hh, states, h_hist);
  k_gates<<<32, 256, 0, stream>>>(states, W_read, b_read, W_write, b_write, W_decay, b_decay,
                                  mscale, read_s, decay_s, write_s);
  dim3 gpj(64, 4);
  k_proj<<<gpj, 256, 0, stream>>>(states, W_he, b_he, proj_bf);
  dim3 gb(393, 16);
  k_base<<<gb, 256, 0, stream>>>(proj_bf, emb_bf, obias, out);
  dim3 gc(4, 8);
  k_corr<<<gc, 64, 0, stream>>>(ids, read_s, decay_s, write_s, out);
}

// Round 9
// 2138.941 us; speedup vs baseline: 1.0147x; 1.0147x over previous
//
#include <hip/hip_runtime.h>
#include <hip/hip_bf16.h>
#include <hip/hip_fp16.h>
#include <math.h>

#define V_SIZE 50257
#define V_PAD  50304   // 393*128
#define E_DIM  256
#define H_DIM  512
#define G_DIM  1536
#define B_SZ   4
#define S_LEN  512

typedef __attribute__((ext_vector_type(8))) short bf16x8;
typedef __attribute__((ext_vector_type(4))) float f32x4;
typedef __attribute__((ext_vector_type(2))) _Float16 h16x2;

__device__ __forceinline__ float sigmoidf_(float x) { return 1.0f / (1.0f + expf(-x)); }
// fast variants for the scan's epilogue (err ~1e-7 rel, threshold is 2e-2)
__device__ __forceinline__ float fsig(float x) { return 1.0f / (1.0f + __expf(-x)); }
__device__ __forceinline__ float ftanh(float x) { return 1.0f - 2.0f / (__expf(2.0f * x) + 1.0f); }

__device__ __forceinline__ h16x2 as_h2(unsigned int u) {
  union { unsigned int u; h16x2 h; } x; x.u = u; return x.h;
}

#if defined(__has_builtin)
#if __has_builtin(__builtin_amdgcn_fdot2)
#define HAVE_FDOT2 1
#endif
#endif
__device__ __forceinline__ float fdot2_(unsigned int a, unsigned int b, float c) {
#ifdef HAVE_FDOT2
  return __builtin_amdgcn_fdot2(as_h2(a), as_h2(b), c, false);
#else
  h16x2 ha = as_h2(a), hb = as_h2(b);
  return c + (float)ha[0] * (float)hb[0] + (float)ha[1] * (float)hb[1];
#endif
}

__device__ __forceinline__ void gload_lds16(const void* g, void* l) {
  __builtin_amdgcn_global_load_lds((const __attribute__((address_space(1))) unsigned int*)g,
                                   (__attribute__((address_space(3))) unsigned int*)l, 16, 0, 0);
}

// ---------------- embedding fp32 -> bf16 (padded to V_PAD rows) ----------------
__global__ __launch_bounds__(256) void k_emb2bf(const float* __restrict__ emb,
                                                __hip_bfloat16* __restrict__ out) {
  const long total = (long)V_PAD * E_DIM;
  for (long i = (long)blockIdx.x * 256 + threadIdx.x; i < total; i += (long)gridDim.x * 256) {
    int row = (int)(i >> 8);
    float v = (row < V_SIZE) ? emb[i] : 0.0f;
    out[i] = __float2bfloat16(v);
  }
}

// ---------------- xg = emb[ids] @ W_ih^T + b_ih  (fp32) ----------------
// grid (12, 128), block 256. tile: 128 g x 16 n, K=256
__global__ __launch_bounds__(256) void k_xg(const int* __restrict__ ids, const float* __restrict__ emb,
                                            const float* __restrict__ W_ih, const float* __restrict__ b_ih,
                                            float* __restrict__ xg) {
  __shared__ float embs[16][260];
  __shared__ float wl[64][133];
  const int g0 = blockIdx.x * 128, n0 = blockIdx.y * 16, tid = threadIdx.x;
  for (int idx = tid; idx < 16 * 256; idx += 256) {
    int n = idx >> 8, e = idx & 255;
    embs[n][e] = emb[(long)ids[n0 + n] * E_DIM + e];
  }
  const int g = tid & 127, ng = tid >> 7;
  float acc[8] = {0.f,0.f,0.f,0.f,0.f,0.f,0.f,0.f};
  for (int e0 = 0; e0 < 256; e0 += 64) {
    __syncthreads();
    for (int idx = tid; idx < 128 * 64; idx += 256) {
      int r = idx >> 6, c = idx & 63;
      wl[c][r] = W_ih[(long)(g0 + r) * E_DIM + e0 + c];
    }
    __syncthreads();
    for (int c = 0; c < 64; ++c) {
      float w = wl[c][g];
      #pragma unroll
      for (int j = 0; j < 8; ++j) acc[j] += w * embs[ng * 8 + j][e0 + c];
    }
  }
  const float bias = b_ih[g0 + g];
  #pragma unroll
  for (int j = 0; j < 8; ++j) {
    int n = n0 + ng * 8 + j;
    xg[(long)n * G_DIM + g0 + g] = acc[j] + bias;
  }
}

// ---------------- persistent GRU scan: 32 wgs x 512 thr ----------------
// R5 u64 data-is-the-flag protocol + delegated poll (R9): wave 0 polls the
// full 512-u64 h vector (lane l owns words [8l,8l+8)) via EIGHT independent
// u64 atomic loads per iteration — same u64<->u64 granularity as the proven
// R5 exchange (single-copy atomic, sentinel can't appear partially), then
// writes them to LDS rawh[] and releases a wg-scope LDS flag; waves 1-7
// spin on the flag (LDS broadcast, zero fabric traffic) and run the
// identical R5 pair-build + fdot2 MAC. Single barrier per step; rawh
// overwrite at t+1 is ordered by the step-t barrier.
#define NWG 32
#define WROWU 261                 // W row stride in u32 pairs (bank-spread)
#define WPLU  (16 * WROWU)
#define HROWU 260                 // hp row stride in u32 pairs
__global__ __launch_bounds__(512, 1) void k_scan(const float* __restrict__ xg,
                                                 const float* __restrict__ W_hh,
                                                 const float* __restrict__ b_hh,
                                                 float* __restrict__ states,
                                                 unsigned long long* __restrict__ h_hist) {
  __shared__ unsigned int Wp[3 * WPLU];         // 50,112 B (f16 pairs)
  __shared__ unsigned int hp[4 * HROWU];        //  4,160 B (f16 pairs, per-wave-private slices)
  __shared__ float red[2][8][16][12];           // 12,288 B partials [buf][wave][il][q*4+b]
  __shared__ unsigned long long rawh[512];      //  4,096 B raw h words for this step
  __shared__ int ready;                         // step counter flag
  const int wg = blockIdx.x, tid = threadIdx.x;
  const int i0 = wg * 16;
  // stage W slice as f16 pairs
  for (int e = tid; e < 3 * 16 * 256; e += 512) {
    int q = e >> 12, i = (e >> 8) & 15, p = e & 255;
    float2 w2 = reinterpret_cast<const float2*>(W_hh + (long)((q << 9) + i0 + i) * H_DIM)[p];
    unsigned int pk = (unsigned int)__half_as_ushort(__float2half(w2.x)) |
                      ((unsigned int)__half_as_ushort(__float2half(w2.y)) << 16);
    Wp[q * WPLU + i * WROWU + p] = pk;
  }
  if (tid == 0) ready = 0;
  const int wave = tid >> 6, l = tid & 63, il = l >> 2, part = l & 3;
  const int ii = tid >> 2, bb = tid & 3;        // epilogue mapping (wave 0)
  const int pidx = tid >> 1;                    // pair index this thread fills
  float h_prev = 0.0f;
  float bhr = 0.f, bhz = 0.f, bhn = 0.f;
  if (tid < 64) { bhr = b_hh[i0 + ii]; bhz = b_hh[512 + i0 + ii]; bhn = b_hh[1024 + i0 + ii]; }
  __syncthreads();

  for (int t = 0; t < S_LEN; ++t) {
    // xg prefetch for the epilogue (in flight during poll+MAC)
    float xr_v = 0.f, xz_v = 0.f, xn_v = 0.f;
    if (tid < 64) {
      const float* xgrow = xg + (long)(bb * S_LEN + t) * G_DIM + i0 + ii;
      xr_v = xgrow[0]; xz_v = xgrow[512]; xn_v = xgrow[1024];
    }
    float acc[3][4] = {{0.f,0.f,0.f,0.f},{0.f,0.f,0.f,0.f},{0.f,0.f,0.f,0.f}};
    if (t > 0) {
      if (wave == 0) {
        // delegated poll: lane l owns h words [8l, 8l+8) of step t-1
        const unsigned long long* hb = h_hist + (long)(t - 1) * 512 + (l << 3);
        unsigned long long w[8];
        bool ok;
        do {
          #pragma unroll
          for (int k = 0; k < 8; ++k)
            w[k] = __hip_atomic_load(hb + k, __ATOMIC_RELAXED, __HIP_MEMORY_SCOPE_AGENT);
          ok = true;
          #pragma unroll
          for (int k = 0; k < 8; ++k) ok &= (w[k] != 0xFFFFFFFFFFFFFFFFull);
        } while (!ok);
        #pragma unroll
        for (int k = 0; k < 8; ++k) rawh[(l << 3) + k] = w[k];
        asm volatile("s_waitcnt lgkmcnt(0)" ::: "memory");
        if (l == 0)
          __hip_atomic_store(&ready, t, __ATOMIC_RELEASE, __HIP_MEMORY_SCOPE_WORKGROUP);
      }
      while (__hip_atomic_load(&ready, __ATOMIC_ACQUIRE, __HIP_MEMORY_SCOPE_WORKGROUP) < t) {}
      const unsigned long long v = rawh[tid];
      const unsigned int lo = (unsigned int)v, hi = (unsigned int)(v >> 32);
      const unsigned int plo = __shfl_xor(lo, 1), phi = __shfl_xor(hi, 1);
      if ((tid & 1) == 0) {       // even: build batch 0,1 pairs for cols (c, c+1)
        hp[pidx]         = (lo & 0xffffu) | (plo << 16);
        hp[HROWU + pidx] = (lo >> 16) | (plo & 0xffff0000u);
      } else {                    // odd: build batch 2,3 pairs
        hp[2 * HROWU + pidx] = (phi & 0xffffu) | (hi << 16);
        hp[3 * HROWU + pidx] = (phi >> 16) | (hi & 0xffff0000u);
      }
      // per-wave-private LDS region: wave-synchronous RAW, no barrier
      const int pbase = (wave << 5) + (part << 3);
      #pragma unroll
      for (int j = 0; j < 8; ++j) {
        const int p = pbase + j;
        const unsigned int w_r = Wp[il * WROWU + p];
        const unsigned int w_z = Wp[WPLU + il * WROWU + p];
        const unsigned int w_n = Wp[2 * WPLU + il * WROWU + p];
        const unsigned int h0 = hp[p];
        const unsigned int h1 = hp[HROWU + p];
        const unsigned int h2 = hp[2 * HROWU + p];
        const unsigned int h3 = hp[3 * HROWU + p];
        acc[0][0] = fdot2_(w_r, h0, acc[0][0]); acc[0][1] = fdot2_(w_r, h1, acc[0][1]);
        acc[0][2] = fdot2_(w_r, h2, acc[0][2]); acc[0][3] = fdot2_(w_r, h3, acc[0][3]);
        acc[1][0] = fdot2_(w_z, h0, acc[1][0]); acc[1][1] = fdot2_(w_z, h1, acc[1][1]);
        acc[1][2] = fdot2_(w_z, h2, acc[1][2]); acc[1][3] = fdot2_(w_z, h3, acc[1][3]);
        acc[2][0] = fdot2_(w_n, h0, acc[2][0]); acc[2][1] = fdot2_(w_n, h1, acc[2][1]);
        acc[2][2] = fdot2_(w_n, h2, acc[2][2]); acc[2][3] = fdot2_(w_n, h3, acc[2][3]);
      }
    }
    // reduce over 'part' (4 lanes), stash per-wave partials
    #pragma unroll
    for (int q = 0; q < 3; ++q)
      #pragma unroll
      for (int b = 0; b < 4; ++b) {
        float v = acc[q][b];
        v += __shfl_xor(v, 1);
        v += __shfl_xor(v, 2);
        if (part == 0) red[t & 1][wave][il][q * 4 + b] = v;
      }
    __syncthreads();                             // the ONE barrier per step
    if (tid < 64) {
      float hr = bhr, hz = bhz, hn = bhn;
      #pragma unroll
      for (int w = 0; w < 8; ++w) {
        hr += red[t & 1][w][ii][0 + bb];
        hz += red[t & 1][w][ii][4 + bb];
        hn += red[t & 1][w][ii][8 + bb];
      }
      float r  = fsig(xr_v + hr);
      float z  = fsig(xz_v + hz);
      float nn = ftanh(xn_v + r * hn);
      float h_new = (1.0f - z) * nn + z * h_prev;
      h_prev = h_new;
      // publish FIRST (critical path): one u64 {b0,b1,b2,b3} per row
      unsigned int hu = (unsigned int)__half_as_ushort(__float2half(h_new));
      unsigned int v1 = __shfl_down(hu, 1);
      unsigned int v2 = __shfl_down(hu, 2);
      unsigned int v3 = __shfl_down(hu, 3);
      if (bb == 0) {
        unsigned long long pk = (unsigned long long)(hu | (v1 << 16)) |
                                ((unsigned long long)(v2 | (v3 << 16)) << 32);
        __hip_atomic_store(h_hist + (long)t * 512 + i0 + ii, pk,
                           __ATOMIC_RELAXED, __HIP_MEMORY_SCOPE_AGENT);
      }
      states[(long)(bb * S_LEN + t) * H_DIM + i0 + ii] = h_new;
    }
    // no trailing barrier: hp per-wave-private, red double-buffered,
    // rawh overwrite ordered by this iteration's barrier
  }
}

// ---------------- read/decay/write gates (wave-per-row, coalesced) ----------------
__global__ __launch_bounds__(256) void k_gates(const float* __restrict__ states,
     const float* __restrict__ W_read, const float* __restrict__ b_read,
     const float* __restrict__ W_write, const float* __restrict__ b_write,
     const float* __restrict__ W_decay, const float* __restrict__ b_decay,
     const float* __restrict__ mscale,
     float* __restrict__ read_s, float* __restrict__ decay_s, float* __restrict__ write_s) {
  __shared__ float wr[512], ww[512], wd[512];
  const int tid = threadIdx.x;
  for (int i = tid; i < 512; i += 256) { wr[i] = W_read[i]; ww[i] = W_write[i]; wd[i] = W_decay[i]; }
  __syncthreads();
  const int wave = tid >> 6, l = tid & 63;
  const float br = b_read[0], bw = b_write[0], bd = b_decay[0], ms = mscale[0];
  for (int r = 0; r < 16; ++r) {
    const int n = blockIdx.x * 64 + wave * 16 + r;
    const float* st = states + (long)n * H_DIM;
    float ar = 0.f, aw = 0.f, ad = 0.f;
    #pragma unroll
    for (int h0 = 0; h0 < 512; h0 += 64) {
      float s = st[h0 + l];
      ar += s * wr[h0 + l]; aw += s * ww[h0 + l]; ad += s * wd[h0 + l];
    }
    #pragma unroll
    for (int k = 1; k < 64; k <<= 1) {
      ar += __shfl_xor(ar, k); aw += __shfl_xor(aw, k); ad += __shfl_xor(ad, k);
    }
    if (l == 0) {
      read_s[n]  = sigmoidf_(ar + br) * ms;
      write_s[n] = sigmoidf_(aw + bw);
      decay_s[n] = sigmoidf_(ad + bd);
    }
  }
}

// ---------------- proj = states @ W_he^T + b_he -> bf16 ----------------
__global__ __launch_bounds__(256) void k_proj(const float* __restrict__ states,
                                              const float* __restrict__ W_he,
                                              const float* __restrict__ b_he,
                                              __hip_bfloat16* __restrict__ proj) {
  __shared__ float sts[32][64];
  __shared__ float wle[64][69];
  const int n0 = blockIdx.x * 32, e0 = blockIdx.y * 64, tid = threadIdx.x;
  const int e = tid & 63, ng = tid >> 6;
  float acc[8] = {0.f,0.f,0.f,0.f,0.f,0.f,0.f,0.f};
  for (int h0 = 0; h0 < 512; h0 += 64) {
    __syncthreads();
    for (int idx = tid; idx < 32 * 64; idx += 256) {
      int n = idx >> 6, c = idx & 63;
      sts[n][c] = states[(long)(n0 + n) * H_DIM + h0 + c];
    }
    for (int idx = tid; idx < 64 * 64; idx += 256) {
      int r = idx >> 6, c = idx & 63;
      wle[c][r] = W_he[(long)(e0 + r) * H_DIM + h0 + c];
    }
    __syncthreads();
    for (int c = 0; c < 64; ++c) {
      float w = wle[c][e];
      #pragma unroll
      for (int j = 0; j < 8; ++j) acc[j] += w * sts[ng * 8 + j][c];
    }
  }
  const float bias = b_he[e0 + e];
  #pragma unroll
  for (int j = 0; j < 8; ++j) {
    int n = n0 + ng * 8 + j;
    proj[(long)n * E_DIM + e0 + e] = __float2bfloat16(acc[j] + bias);
  }
}

// ---------------- base = proj @ emb^T + output_bias (bf16 MFMA) ----------------
// grid (393, 16), block 256 (4 waves 2x2), tile 128x128, BK=32, K=256
__global__ __launch_bounds__(256) void k_base(const __hip_bfloat16* __restrict__ A,
                                              const __hip_bfloat16* __restrict__ Bm,
                                              const float* __restrict__ obias,
                                              float* __restrict__ C) {
  __shared__ unsigned short As[128 * 32], Bs[128 * 32];
  const int n0 = blockIdx.x * 128, m0 = blockIdx.y * 128, tid = threadIdx.x;
  const int wid = tid >> 6, l = tid & 63;
  const int wm = wid >> 1, wn = wid & 1;
  f32x4 acc[4][4];
  #pragma unroll
  for (int mi = 0; mi < 4; ++mi)
    #pragma unroll
    for (int ni = 0; ni < 4; ++ni) acc[mi][ni] = (f32x4){0.f, 0.f, 0.f, 0.f};

  for (int kk = 0; kk < 256; kk += 32) {
    __syncthreads();
    #pragma unroll
    for (int s = 0; s < 2; ++s) {
      const int cibase = wid * 128 + s * 64;
      const int ci = cibase + l;
      const int row = ci >> 2, cq = ci & 3;
      gload_lds16(A + (long)(m0 + row) * E_DIM + kk + cq * 8, As + cibase * 8);
      gload_lds16(Bm + (long)(n0 + row) * E_DIM + kk + cq * 8, Bs + cibase * 8);
    }
    __syncthreads();
    bf16x8 af[4], bfr[4];
    const int krow = (l >> 4) * 8;
    #pragma unroll
    for (int mi = 0; mi < 4; ++mi) {
      int row = wm * 64 + mi * 16 + (l & 15);
      af[mi] = *reinterpret_cast<const bf16x8*>(&As[row * 32 + krow]);
    }
    #pragma unroll
    for (int ni = 0; ni < 4; ++ni) {
      int row = wn * 64 + ni * 16 + (l & 15);
      bfr[ni] = *reinterpret_cast<const bf16x8*>(&Bs[row * 32 + krow]);
    }
    #pragma unroll
    for (int mi = 0; mi < 4; ++mi)
      #pragma unroll
      for (int ni = 0; ni < 4; ++ni)
        acc[mi][ni] = __builtin_amdgcn_mfma_f32_16x16x32_bf16(af[mi], bfr[ni], acc[mi][ni], 0, 0, 0);
  }
  #pragma unroll
  for (int mi = 0; mi < 4; ++mi) {
    const int rowb = m0 + wm * 64 + mi * 16 + (l >> 4) * 4;
    #pragma unroll
    for (int ni = 0; ni < 4; ++ni) {
      const int col = n0 + wn * 64 + ni * 16 + (l & 15);
      if (col < V_SIZE) {
        const float ob = obias[col];
        #pragma unroll
        for (int r = 0; r < 4; ++r)
          C[(long)(rowb + r) * V_SIZE + col] = acc[mi][ni][r] + ob;
      }
    }
  }
}

// ---------------- sparse memory correction: out[b,t,v] += read*m ----------------
// grid (4 batches, 8 owner-chunks) x 64 threads: owner-per-lane
__global__ __launch_bounds__(64) void k_corr(const int* __restrict__ ids,
                                             const float* __restrict__ read_s,
                                             const float* __restrict__ decay_s,
                                             const float* __restrict__ write_s,
                                             float* __restrict__ out) {
  __shared__ int ids_s[512];
  __shared__ float rd[512], dc[512], wrs[512];
  const int b = blockIdx.x, c = blockIdx.y, l = threadIdx.x;
  for (int t = l; t < 512; t += 64) {
    int n = b * 512 + t;
    ids_s[t] = ids[n]; rd[t] = read_s[n]; dc[t] = decay_s[n]; wrs[t] = write_s[n];
  }
  __syncthreads();
  const int j = c * 64 + l;
  const int v = ids_s[j];
  for (int jj = 0; jj < j; ++jj) if (ids_s[jj] == v) return;  // not the owner
  float m = wrs[j];
  float* outb = out + (long)b * S_LEN * V_SIZE + v;
  for (int t = j + 1; t < 512; ++t) {
    outb[(long)t * V_SIZE] += rd[t] * m;
    m *= dc[t];
    if (ids_s[t] == v) m += wrs[t];
  }
}

extern "C" void kernel_launch(void* const* d_in, const int* in_sizes, int n_in,
                              void* d_out, int out_size, void* d_ws, size_t ws_size,
                              hipStream_t stream) {
  const int*   ids     = (const int*)d_in[0];
  const float* emb     = (const float*)d_in[1];
  const float* W_ih    = (const float*)d_in[2];
  const float* W_hh    = (const float*)d_in[3];
  const float* b_ih    = (const float*)d_in[4];
  const float* b_hh    = (const float*)d_in[5];
  const float* W_he    = (const float*)d_in[6];
  const float* b_he    = (const float*)d_in[7];
  const float* obias   = (const float*)d_in[8];
  const float* W_read  = (const float*)d_in[9];
  const float* b_read  = (const float*)d_in[10];
  const float* W_write = (const float*)d_in[11];
  const float* b_write = (const float*)d_in[12];
  const float* W_decay = (const float*)d_in[13];
  const float* b_decay = (const float*)d_in[14];
  const float* mscale  = (const float*)d_in[15];

  // ws: emb_bf16 (25.7MB) + proj_bf16 (1MB) + gate scalars (24KB)
  char* ws = (char*)d_ws;
  __hip_bfloat16* emb_bf  = (__hip_bfloat16*)ws;                    // V_PAD*E*2 = 25,755,648
  __hip_bfloat16* proj_bf = (__hip_bfloat16*)(ws + 25755648);       // 1,048,576
  float* read_s  = (float*)(ws + 26804224);
  float* decay_s = (float*)(ws + 26812416);
  float* write_s = (float*)(ws + 26820608);

  // scratch that dies before k_base lives inside d_out (412MB):
  char* ob = (char*)d_out;
  float* xg  = (float*)ob;                                   // 12,582,912 B
  float* states = (float*)(ob + 12582912);                   //  4,194,304 B
  unsigned long long* h_hist = (unsigned long long*)(ob + 16777216); // 2,097,152 B
  float* out = (float*)d_out;

  hipMemsetAsync(h_hist, 0xFF, (size_t)S_LEN * 512 * sizeof(unsigned long long), stream);
  k_emb2bf<<<2048, 256, 0, stream>>>(emb, emb_bf);
  dim3 gxg(12, 128);
  k_xg<<<gxg, 256, 0, stream>>>(ids, emb, W_ih, b_ih, xg);
  k_scan<<<NWG, 512, 0, stream>>>(xg, W_hh, b_hh, states, h_hist);
  k_gates<<<32, 256, 0, stream>>>(states, W_read, b_read, W_write, b_write, W_decay, b_decay,
                                  mscale, read_s, decay_s, write_s);
  dim3 gpj(64, 4);
  k_proj<<<gpj, 256, 0, stream>>>(states, W_he, b_he, proj_bf);
  dim3 gb(393, 16);
  k_base<<<gb, 256, 0, stream>>>(proj_bf, emb_bf, obias, out);
  dim3 gc(4, 8);
  k_corr<<<gc, 64, 0, stream>>>(ids, read_s, decay_s, write_s, out);
}

// Round 11
// 1642.596 us; speedup vs baseline: 1.3213x; 1.3022x over previous
//
#include <hip/hip_runtime.h>
#include <hip/hip_bf16.h>
#include <hip/hip_fp16.h>
#include <math.h>

#define V_SIZE 50257
#define V_PAD  50304   // 393*128
#define E_DIM  256
#define H_DIM  512
#define G_DIM  1536
#define B_SZ   4
#define S_LEN  512

typedef __attribute__((ext_vector_type(8))) short bf16x8;
typedef __attribute__((ext_vector_type(4))) float f32x4;
typedef __attribute__((ext_vector_type(2))) _Float16 h16x2;

__device__ __forceinline__ float sigmoidf_(float x) { return 1.0f / (1.0f + expf(-x)); }
__device__ __forceinline__ float fsig(float x) { return 1.0f / (1.0f + __expf(-x)); }
__device__ __forceinline__ float ftanh(float x) { return 1.0f - 2.0f / (__expf(2.0f * x) + 1.0f); }

__device__ __forceinline__ h16x2 as_h2(unsigned int u) {
  union { unsigned int u; h16x2 h; } x; x.u = u; return x.h;
}
#if defined(__has_builtin)
#if __has_builtin(__builtin_amdgcn_fdot2)
#define HAVE_FDOT2 1
#endif
#endif
__device__ __forceinline__ float fdot2_(unsigned int a, unsigned int b, float c) {
#ifdef HAVE_FDOT2
  return __builtin_amdgcn_fdot2(as_h2(a), as_h2(b), c, false);
#else
  h16x2 ha = as_h2(a), hb = as_h2(b);
  return c + (float)ha[0] * (float)hb[0] + (float)ha[1] * (float)hb[1];
#endif
}
__device__ __forceinline__ void gload_lds16(const void* g, void* l) {
  __builtin_amdgcn_global_load_lds((const __attribute__((address_space(1))) unsigned int*)g,
                                   (__attribute__((address_space(3))) unsigned int*)l, 16, 0, 0);
}

// ---------------- xg = emb[ids] @ W_ih^T + b_ih  (fp32) ----------------
__global__ __launch_bounds__(256) void k_xg(const int* __restrict__ ids, const float* __restrict__ emb,
                                            const float* __restrict__ W_ih, const float* __restrict__ b_ih,
                                            float* __restrict__ xg) {
  __shared__ float embs[16][260];
  __shared__ float wl[64][133];
  const int g0 = blockIdx.x * 128, n0 = blockIdx.y * 16, tid = threadIdx.x;
  for (int idx = tid; idx < 16 * 256; idx += 256) {
    int n = idx >> 8, e = idx & 255;
    embs[n][e] = emb[(long)ids[n0 + n] * E_DIM + e];
  }
  const int g = tid & 127, ng = tid >> 7;
  float acc[8] = {0.f,0.f,0.f,0.f,0.f,0.f,0.f,0.f};
  for (int e0 = 0; e0 < 256; e0 += 64) {
    __syncthreads();
    for (int idx = tid; idx < 128 * 64; idx += 256) {
      int r = idx >> 6, c = idx & 63;
      wl[c][r] = W_ih[(long)(g0 + r) * E_DIM + e0 + c];
    }
    __syncthreads();
    for (int c = 0; c < 64; ++c) {
      float w = wl[c][g];
      #pragma unroll
      for (int j = 0; j < 8; ++j) acc[j] += w * embs[ng * 8 + j][e0 + c];
    }
  }
  const float bias = b_ih[g0 + g];
  #pragma unroll
  for (int j = 0; j < 8; ++j) {
    int n = n0 + ng * 8 + j;
    xg[(long)n * G_DIM + g0 + g] = acc[j] + bias;
  }
}

// ---------------- scan (R5 verbatim, bid<32) + emb->bf16 (bid>=32) ----------------
#define NWG 32
#define NEXTRA 216       // emb2bf blocks
#define WROWU 261
#define WPLU  (16 * WROWU)
#define HROWU 260
__global__ __launch_bounds__(512, 1) void k_scan(const float* __restrict__ xg,
                                                 const float* __restrict__ W_hh,
                                                 const float* __restrict__ b_hh,
                                                 float* __restrict__ states,
                                                 unsigned long long* __restrict__ h_hist,
                                                 const float* __restrict__ emb,
                                                 __hip_bfloat16* __restrict__ emb_bf) {
  __shared__ unsigned int Wp[3 * WPLU];
  __shared__ unsigned int hp[4 * HROWU];
  __shared__ float red[2][8][16][12];
  const int bid = blockIdx.x, tid = threadIdx.x;

  if (bid >= NWG) {
    // independent emb fp32->bf16 conversion (no shared state with the scan)
    const long total = (long)V_PAD * E_DIM;
    for (long i = (long)(bid - NWG) * 512 + tid; i < total; i += (long)NEXTRA * 512) {
      int row = (int)(i >> 8);
      float v = (row < V_SIZE) ? emb[i] : 0.0f;
      emb_bf[i] = __float2bfloat16(v);
    }
    return;
  }

  const int wg = bid;
  const int i0 = wg * 16;
  for (int e = tid; e < 3 * 16 * 256; e += 512) {
    int q = e >> 12, i = (e >> 8) & 15, p = e & 255;
    float2 w2 = reinterpret_cast<const float2*>(W_hh + (long)((q << 9) + i0 + i) * H_DIM)[p];
    unsigned int pk = (unsigned int)__half_as_ushort(__float2half(w2.x)) |
                      ((unsigned int)__half_as_ushort(__float2half(w2.y)) << 16);
    Wp[q * WPLU + i * WROWU + p] = pk;
  }
  const int wave = tid >> 6, l = tid & 63, il = l >> 2, part = l & 3;
  const int ii = tid >> 2, bb = tid & 3;
  const int pidx = tid >> 1;
  float h_prev = 0.0f;
  float bhr = 0.f, bhz = 0.f, bhn = 0.f;
  if (tid < 64) { bhr = b_hh[i0 + ii]; bhz = b_hh[512 + i0 + ii]; bhn = b_hh[1024 + i0 + ii]; }
  __syncthreads();

  for (int t = 0; t < S_LEN; ++t) {
    float xr_v = 0.f, xz_v = 0.f, xn_v = 0.f;
    if (tid < 64) {
      const float* xgrow = xg + (long)(bb * S_LEN + t) * G_DIM + i0 + ii;
      xr_v = xgrow[0]; xz_v = xgrow[512]; xn_v = xgrow[1024];
    }
    float acc[3][4] = {{0.f,0.f,0.f,0.f},{0.f,0.f,0.f,0.f},{0.f,0.f,0.f,0.f}};
    if (t > 0) {
      const unsigned long long* hb = h_hist + (long)(t - 1) * 512;
      unsigned long long v;
      do {
        v = __hip_atomic_load(hb + tid, __ATOMIC_RELAXED, __HIP_MEMORY_SCOPE_AGENT);
      } while (v == 0xFFFFFFFFFFFFFFFFull);
      const unsigned int lo = (unsigned int)v, hi = (unsigned int)(v >> 32);
      const unsigned int plo = __shfl_xor(lo, 1), phi = __shfl_xor(hi, 1);
      if ((tid & 1) == 0) {
        hp[pidx]         = (lo & 0xffffu) | (plo << 16);
        hp[HROWU + pidx] = (lo >> 16) | (plo & 0xffff0000u);
      } else {
        hp[2 * HROWU + pidx] = (phi & 0xffffu) | (hi << 16);
        hp[3 * HROWU + pidx] = (phi >> 16) | (hi & 0xffff0000u);
      }
      const int pbase = (wave << 5) + (part << 3);
      #pragma unroll
      for (int j = 0; j < 8; ++j) {
        const int p = pbase + j;
        const unsigned int w_r = Wp[il * WROWU + p];
        const unsigned int w_z = Wp[WPLU + il * WROWU + p];
        const unsigned int w_n = Wp[2 * WPLU + il * WROWU + p];
        const unsigned int h0 = hp[p];
        const unsigned int h1 = hp[HROWU + p];
        const unsigned int h2 = hp[2 * HROWU + p];
        const unsigned int h3 = hp[3 * HROWU + p];
        acc[0][0] = fdot2_(w_r, h0, acc[0][0]); acc[0][1] = fdot2_(w_r, h1, acc[0][1]);
        acc[0][2] = fdot2_(w_r, h2, acc[0][2]); acc[0][3] = fdot2_(w_r, h3, acc[0][3]);
        acc[1][0] = fdot2_(w_z, h0, acc[1][0]); acc[1][1] = fdot2_(w_z, h1, acc[1][1]);
        acc[1][2] = fdot2_(w_z, h2, acc[1][2]); acc[1][3] = fdot2_(w_z, h3, acc[1][3]);
        acc[2][0] = fdot2_(w_n, h0, acc[2][0]); acc[2][1] = fdot2_(w_n, h1, acc[2][1]);
        acc[2][2] = fdot2_(w_n, h2, acc[2][2]); acc[2][3] = fdot2_(w_n, h3, acc[2][3]);
      }
    }
    #pragma unroll
    for (int q = 0; q < 3; ++q)
      #pragma unroll
      for (int b = 0; b < 4; ++b) {
        float v = acc[q][b];
        v += __shfl_xor(v, 1);
        v += __shfl_xor(v, 2);
        if (part == 0) red[t & 1][wave][il][q * 4 + b] = v;
      }
    __syncthreads();
    if (tid < 64) {
      float hr = bhr, hz = bhz, hn = bhn;
      #pragma unroll
      for (int w = 0; w < 8; ++w) {
        hr += red[t & 1][w][ii][0 + bb];
        hz += red[t & 1][w][ii][4 + bb];
        hn += red[t & 1][w][ii][8 + bb];
      }
      float r  = fsig(xr_v + hr);
      float z  = fsig(xz_v + hz);
      float nn = ftanh(xn_v + r * hn);
      float h_new = (1.0f - z) * nn + z * h_prev;
      h_prev = h_new;
      unsigned int hu = (unsigned int)__half_as_ushort(__float2half(h_new));
      unsigned int v1 = __shfl_down(hu, 1);
      unsigned int v2 = __shfl_down(hu, 2);
      unsigned int v3 = __shfl_down(hu, 3);
      if (bb == 0) {
        unsigned long long pk = (unsigned long long)(hu | (v1 << 16)) |
                                ((unsigned long long)(v2 | (v3 << 16)) << 32);
        __hip_atomic_store(h_hist + (long)t * 512 + i0 + ii, pk,
                           __ATOMIC_RELAXED, __HIP_MEMORY_SCOPE_AGENT);
      }
      states[(long)(bb * S_LEN + t) * H_DIM + i0 + ii] = h_new;
    }
  }
}

// ---------------- proj (bid<256) + gates (bid>=256), block 256 ----------------
__global__ __launch_bounds__(256) void k_projgates(const float* __restrict__ states,
     const float* __restrict__ W_he, const float* __restrict__ b_he,
     __hip_bfloat16* __restrict__ proj,
     const float* __restrict__ W_read, const float* __restrict__ b_read,
     const float* __restrict__ W_write, const float* __restrict__ b_write,
     const float* __restrict__ W_decay, const float* __restrict__ b_decay,
     const float* __restrict__ mscale,
     float* __restrict__ read_s, float* __restrict__ decay_s, float* __restrict__ write_s) {
  __shared__ float sm[6464];     // proj: sts[32*64]+wle[64*69]=25856B; gates: 3*512 floats
  const int bid = blockIdx.x, tid = threadIdx.x;
  if (bid < 256) {
    float* sts = sm;             // [32][64]
    float* wle = sm + 2048;      // [64][69]
    const int n0 = (bid & 63) * 32, e0 = (bid >> 6) * 64;
    const int e = tid & 63, ng = tid >> 6;
    float acc[8] = {0.f,0.f,0.f,0.f,0.f,0.f,0.f,0.f};
    for (int h0 = 0; h0 < 512; h0 += 64) {
      __syncthreads();
      for (int idx = tid; idx < 32 * 64; idx += 256) {
        int n = idx >> 6, c = idx & 63;
        sts[n * 64 + c] = states[(long)(n0 + n) * H_DIM + h0 + c];
      }
      for (int idx = tid; idx < 64 * 64; idx += 256) {
        int r = idx >> 6, c = idx & 63;
        wle[c * 69 + r] = W_he[(long)(e0 + r) * H_DIM + h0 + c];
      }
      __syncthreads();
      for (int c = 0; c < 64; ++c) {
        float w = wle[c * 69 + e];
        #pragma unroll
        for (int j = 0; j < 8; ++j) acc[j] += w * sts[(ng * 8 + j) * 64 + c];
      }
    }
    const float bias = b_he[e0 + e];
    #pragma unroll
    for (int j = 0; j < 8; ++j) {
      int n = n0 + ng * 8 + j;
      proj[(long)n * E_DIM + e0 + e] = __float2bfloat16(acc[j] + bias);
    }
  } else {
    float* wr = sm; float* ww = sm + 512; float* wd = sm + 1024;
    for (int i = tid; i < 512; i += 256) { wr[i] = W_read[i]; ww[i] = W_write[i]; wd[i] = W_decay[i]; }
    __syncthreads();
    const int wave = tid >> 6, l = tid & 63;
    const float br = b_read[0], bw = b_write[0], bd = b_decay[0], ms = mscale[0];
    for (int r = 0; r < 16; ++r) {
      const int n = (bid - 256) * 64 + wave * 16 + r;
      const float* st = states + (long)n * H_DIM;
      float ar = 0.f, aw = 0.f, ad = 0.f;
      #pragma unroll
      for (int h0 = 0; h0 < 512; h0 += 64) {
        float s = st[h0 + l];
        ar += s * wr[h0 + l]; aw += s * ww[h0 + l]; ad += s * wd[h0 + l];
      }
      #pragma unroll
      for (int k = 1; k < 64; k <<= 1) {
        ar += __shfl_xor(ar, k); aw += __shfl_xor(aw, k); ad += __shfl_xor(ad, k);
      }
      if (l == 0) {
        read_s[n]  = sigmoidf_(ar + br) * ms;
        write_s[n] = sigmoidf_(aw + bw);
        decay_s[n] = sigmoidf_(ad + bd);
      }
    }
  }
}

// ---------------- base = proj @ emb^T + obias (bf16 MFMA, XCD-swizzled 1D) ----------------
// 6288 = 8 * 786 blocks; swz keeps same-v (B-tile-sharing) blocks on one XCD.
__global__ __launch_bounds__(256) void k_base(const __hip_bfloat16* __restrict__ A,
                                              const __hip_bfloat16* __restrict__ Bm,
                                              const float* __restrict__ obias,
                                              float* __restrict__ C) {
  __shared__ unsigned short As[128 * 32], Bs[128 * 32];
  const int swz = (blockIdx.x & 7) * 786 + (blockIdx.x >> 3);
  const int m0 = (swz & 15) * 128, n0 = (swz >> 4) * 128;
  const int tid = threadIdx.x;
  const int wid = tid >> 6, l = tid & 63;
  const int wm = wid >> 1, wn = wid & 1;
  f32x4 acc[4][4];
  #pragma unroll
  for (int mi = 0; mi < 4; ++mi)
    #pragma unroll
    for (int ni = 0; ni < 4; ++ni) acc[mi][ni] = (f32x4){0.f, 0.f, 0.f, 0.f};

  for (int kk = 0; kk < 256; kk += 32) {
    __syncthreads();
    #pragma unroll
    for (int s = 0; s < 2; ++s) {
      const int cibase = wid * 128 + s * 64;
      const int ci = cibase + l;
      const int row = ci >> 2, cq = ci & 3;
      gload_lds16(A + (long)(m0 + row) * E_DIM + kk + cq * 8, As + cibase * 8);
      gload_lds16(Bm + (long)(n0 + row) * E_DIM + kk + cq * 8, Bs + cibase * 8);
    }
    __syncthreads();
    bf16x8 af[4], bfr[4];
    const int krow = (l >> 4) * 8;
    #pragma unroll
    for (int mi = 0; mi < 4; ++mi) {
      int row = wm * 64 + mi * 16 + (l & 15);
      af[mi] = *reinterpret_cast<const bf16x8*>(&As[row * 32 + krow]);
    }
    #pragma unroll
    for (int ni = 0; ni < 4; ++ni) {
      int row = wn * 64 + ni * 16 + (l & 15);
      bfr[ni] = *reinterpret_cast<const bf16x8*>(&Bs[row * 32 + krow]);
    }
    #pragma unroll
    for (int mi = 0; mi < 4; ++mi)
      #pragma unroll
      for (int ni = 0; ni < 4; ++ni)
        acc[mi][ni] = __builtin_amdgcn_mfma_f32_16x16x32_bf16(af[mi], bfr[ni], acc[mi][ni], 0, 0, 0);
  }
  #pragma unroll
  for (int mi = 0; mi < 4; ++mi) {
    const int rowb = m0 + wm * 64 + mi * 16 + (l >> 4) * 4;
    #pragma unroll
    for (int ni = 0; ni < 4; ++ni) {
      const int col = n0 + wn * 64 + ni * 16 + (l & 15);
      if (col < V_SIZE) {
        const float ob = obias[col];
        #pragma unroll
        for (int r = 0; r < 4; ++r)
          C[(long)(rowb + r) * V_SIZE + col] = acc[mi][ni][r] + ob;
      }
    }
  }
}

// ---------------- sparse memory correction, latency-parallel ----------------
// grid (4, 512) x 64 threads: wg (b, j). Ownership checked in parallel;
// lane 0 precomputes c[t]=rd[t]*m(t) in LDS (no memory stalls); 64 lanes
// then apply the out[] RMWs in parallel (<=8 latency rounds vs ~500 serial).
__global__ __launch_bounds__(64) void k_corr(const int* __restrict__ ids,
                                             const float* __restrict__ read_s,
                                             const float* __restrict__ decay_s,
                                             const float* __restrict__ write_s,
                                             float* __restrict__ out) {
  __shared__ int ids_s[512];
  __shared__ float rd[512], dc[512], wrs[512], c[512];
  const int b = blockIdx.x, j = blockIdx.y, l = threadIdx.x;
  for (int t = l; t < 512; t += 64) {
    int n = b * 512 + t;
    ids_s[t] = ids[n]; rd[t] = read_s[n]; dc[t] = decay_s[n]; wrs[t] = write_s[n];
  }
  __syncthreads();
  const int v = ids_s[j];
  bool own = true;
  for (int jj = l; jj < j; jj += 64) if (ids_s[jj] == v) own = false;
  if (!__all(own)) return;       // block = one wave
  if (l == 0) {
    float m = wrs[j];
    for (int t = j + 1; t < 512; ++t) {
      c[t] = rd[t] * m;
      m *= dc[t];
      if (ids_s[t] == v) m += wrs[t];
    }
  }
  __syncthreads();
  float* outb = out + (long)b * S_LEN * V_SIZE + v;
  for (int t = j + 1 + l; t < 512; t += 64)
    outb[(long)t * V_SIZE] += c[t];
}

extern "C" void kernel_launch(void* const* d_in, const int* in_sizes, int n_in,
                              void* d_out, int out_size, void* d_ws, size_t ws_size,
                              hipStream_t stream) {
  const int*   ids     = (const int*)d_in[0];
  const float* emb     = (const float*)d_in[1];
  const float* W_ih    = (const float*)d_in[2];
  const float* W_hh    = (const float*)d_in[3];
  const float* b_ih    = (const float*)d_in[4];
  const float* b_hh    = (const float*)d_in[5];
  const float* W_he    = (const float*)d_in[6];
  const float* b_he    = (const float*)d_in[7];
  const float* obias   = (const float*)d_in[8];
  const float* W_read  = (const float*)d_in[9];
  const float* b_read  = (const float*)d_in[10];
  const float* W_write = (const float*)d_in[11];
  const float* b_write = (const float*)d_in[12];
  const float* W_decay = (const float*)d_in[13];
  const float* b_decay = (const float*)d_in[14];
  const float* mscale  = (const float*)d_in[15];

  // ws: emb_bf16 (25.76MB) + proj_bf16 (1MB) + gate scalars
  char* ws = (char*)d_ws;
  __hip_bfloat16* emb_bf  = (__hip_bfloat16*)ws;                  // 25,755,648 B
  __hip_bfloat16* proj_bf = (__hip_bfloat16*)(ws + 25755648);     //  1,048,576 B
  float* read_s  = (float*)(ws + 26804224);
  float* decay_s = (float*)(ws + 26812416);
  float* write_s = (float*)(ws + 26820608);

  // scratch that dies before k_base lives inside d_out (412MB):
  char* ob = (char*)d_out;
  float* xg     = (float*)ob;                                    // 12,582,912 B
  float* states = (float*)(ob + 12582912);                       //  4,194,304 B
  unsigned long long* h_hist = (unsigned long long*)(ob + 16777216); // 2,097,152 B
  float* out = (float*)d_out;

  hipMemsetAsync(h_hist, 0xFF, (size_t)S_LEN * 512 * sizeof(unsigned long long), stream);
  dim3 gxg(12, 128);
  k_xg<<<gxg, 256, 0, stream>>>(ids, emb, W_ih, b_ih, xg);
  k_scan<<<NWG + NEXTRA, 512, 0, stream>>>(xg, W_hh, b_hh, states, h_hist, emb, emb_bf);
  k_projgates<<<288, 256, 0, stream>>>(states, W_he, b_he, proj_bf,
                                       W_read, b_read, W_write, b_write, W_decay, b_decay,
                                       mscale, read_s, decay_s, write_s);
  k_base<<<6288, 256, 0, stream>>>(proj_bf, emb_bf, obias, out);
  dim3 gc(4, 512);
  k_corr<<<gc, 64, 0, stream>>>(ids, read_s, decay_s, write_s, out);
}